// Round 1
// baseline (302.428 us; speedup 1.0000x reference)
//
#include <hip/hip_runtime.h>
#include <hip/hip_bf16.h>
#include <math.h>

#define EPS 1e-3f
// B=4, S=256, D=256, v=128, e=64, c=192, NH=8, DK=8, DV=8

// ws layout (floats):
// 8192   : cK[64], 8256: dK[64], 8320: cV[64], 8384: dV[64]
// 8448   : q_s [B*D*64]  (relu(q)/sqrt(8))
// 73984  : Pd  [B*D*64]  (V_dst @ We[128:256])
// 139520 : sv  [B*S]     (sum of V_src row)
// 140544 : ssv [B*S]     (sumsq of V_src row)
// 141568 : Qs_k[B*S*64]  (g_in-folded V_src @ Wk[0:128])
// 207104 : Qs_v[B*S*64]
// 272640 : Ps  [B*S*64]  (V_src @ We[0:128])
// 338176 : Wcat bf16 [192 n][64 k]  = [g_in*WkE | g_in*WvE | We3]  (12288 ushort)
#define WCAT_OFF 338176

typedef __attribute__((ext_vector_type(8))) short short8;
typedef __attribute__((ext_vector_type(8))) unsigned short ushort8;
typedef __attribute__((ext_vector_type(4))) float floatx4;

__device__ __forceinline__ unsigned short f2bf(float f) {
    __hip_bfloat16 h = __float2bfloat16(f);
    return *reinterpret_cast<unsigned short*>(&h);
}

// Merged precompute: blocks 0..1023 = dst-mode (+ coalesced A_new=1 fill),
// 1024..2047 = src-mode, 2048 = weight-prep. One launch instead of three.
__global__ __launch_bounds__(256) void prep_merged(
        const float* __restrict__ V_src, const float* __restrict__ V_dst,
        const float* __restrict__ g_vd, const float* __restrict__ b_vd,
        const float* __restrict__ g_in, const float* __restrict__ b_in,
        const float* __restrict__ Wq, const float* __restrict__ bq,
        const float* __restrict__ Wk, const float* __restrict__ bk,
        const float* __restrict__ Wv, const float* __restrict__ bv,
        const float* __restrict__ We, float* __restrict__ ws,
        float* __restrict__ out2) {
    int blk = blockIdx.x;
    int tid = threadIdx.x;
    __shared__ float sA[128], sB[128], sC[4];
    if (blk < 1024) {
        // ---- dst-mode: LN(V_dst)->q, Pd; plus A_new = 1.0 fill ----
        float x = 0.f;
        if (tid < 128) { x = V_dst[blk * 128 + tid]; sA[tid] = x; }
        float s1 = x, s2 = x * x;
        #pragma unroll
        for (int o = 1; o <= 32; o <<= 1) { s1 += __shfl_xor(s1, o); s2 += __shfl_xor(s2, o); }
        if (tid < 128 && (tid & 63) == 0) { sC[tid >> 6] = s1; sC[2 + (tid >> 6)] = s2; }
        __syncthreads();
        if (tid < 128) {
            float sum = sC[0] + sC[1], ssq = sC[2] + sC[3];
            float mu = sum * (1.f / 128.f);
            float var = ssq * (1.f / 128.f) - mu * mu;
            float rsig = rsqrtf(var + EPS);
            sB[tid] = (x - mu) * rsig * g_vd[tid] + b_vd[tid];
        }
        __syncthreads();
        if (tid < 128) {
            int n = tid & 63;
            if (tid < 64) {
                float acc = bq[n];
                for (int j = 0; j < 128; j++) acc += sB[j] * Wq[j * 64 + n];
                ws[8448 + blk * 64 + n] = fmaxf(acc, 0.f) * 0.35355339059327373f;
            } else {
                float acc = 0.f;
                for (int j = 0; j < 128; j++) acc += sA[j] * We[(128 + j) * 64 + n];
                ws[73984 + blk * 64 + n] = acc;
            }
        }
        out2[blk * 256 + tid] = 1.0f;   // A_new == softmax over singleton == 1, coalesced
    } else if (blk < 2048) {
        // ---- src-mode: row stats; Qs_k / Qs_v / Ps ----
        int sb = blk - 1024;
        if (tid < 128) sA[tid] = V_src[sb * 128 + tid];
        __syncthreads();
        if (tid < 64) {
            float a = sA[tid], b2 = sA[tid + 64];
            float s1 = a + b2, s2 = a * a + b2 * b2;
            #pragma unroll
            for (int o = 1; o <= 32; o <<= 1) { s1 += __shfl_xor(s1, o); s2 += __shfl_xor(s2, o); }
            if (tid == 0) { ws[139520 + sb] = s1; ws[140544 + sb] = s2; }
        }
        if (tid < 192) {
            int g = tid / 64, n = tid & 63;
            float acc = 0.f;
            if (g == 0) {
                for (int j = 0; j < 128; j++) acc += sA[j] * g_in[j] * Wk[j * 64 + n];
                ws[141568 + sb * 64 + n] = acc;
            } else if (g == 1) {
                for (int j = 0; j < 128; j++) acc += sA[j] * g_in[j] * Wv[j * 64 + n];
                ws[207104 + sb * 64 + n] = acc;
            } else {
                for (int j = 0; j < 128; j++) acc += sA[j] * We[j * 64 + n];
                ws[272640 + sb * 64 + n] = acc;
            }
        }
    } else {
        // ---- weight-prep (folded LN coefficients + bf16 Wcat) ----
        int n = tid & 63;
        if (tid < 64) {
            float c = 0.f, dd = 0.f;
            for (int j = 0; j < 192; j++) { float w = Wk[j * 64 + n]; c += g_in[j] * w; dd += b_in[j] * w; }
            ws[8192 + n] = c; ws[8256 + n] = dd + bk[n];
        } else if (tid < 128) {
            float c = 0.f, dd = 0.f;
            for (int j = 0; j < 192; j++) { float w = Wv[j * 64 + n]; c += g_in[j] * w; dd += b_in[j] * w; }
            ws[8320 + n] = c; ws[8384 + n] = dd + bv[n];
        }
        unsigned short* wcat = (unsigned short*)(ws + WCAT_OFF);
        for (int idx = tid; idx < 12288; idx += 256) {
            int nn = idx >> 6, k = idx & 63;
            float w;
            if (nn < 64)       w = g_in[128 + k] * Wk[(128 + k) * 64 + nn];
            else if (nn < 128) w = g_in[128 + k] * Wv[(128 + k) * 64 + (nn - 64)];
            else               w = We[(256 + k) * 64 + (nn - 128)];
            wcat[idx] = f2bf(w);
        }
    }
}

// Fused per-(b,d) kernel. MFMA accumulators stay in registers; the
// heads-softmax runs directly in MFMA C-layout:
//   n = t*16+col  ->  dk = col&7 (shfl_xor 1,2,4), head = t*2 + (col>>3)
//   (head bit0 = shfl_xor 8, head bits 1..2 = register index t)
// res[] LDS transpose eliminated; Wcat staged in LDS (bank-balanced stride 72).
// LDS 38.7 KB -> 4 blocks/CU with __launch_bounds__(256,4) = 16 waves/CU.
__global__ __launch_bounds__(256, 4) void fused_kernel(
        const float* __restrict__ E, const float* __restrict__ A,
        const float* __restrict__ V_dst,
        const float* __restrict__ Wo, const float* __restrict__ bo,
        const float* __restrict__ be,
        const float* __restrict__ ws,
        float* __restrict__ out0, float* __restrict__ out1) {
    int blk = blockIdx.x;
    int b = blk >> 8, d = blk & 255;
    int tid = threadIdx.x, wv = tid >> 6, lane = tid & 63;
    int col = lane & 15, quad = lane >> 4;

    __shared__ __align__(16) unsigned short Ebf[64 * 72];   // 64 rows x 64 bf16, stride 72
    __shared__ __align__(16) unsigned short Wc[192 * 72];   // Wcat, stride 72 (bank-balanced)
    __shared__ float ssum[64], sssq[64];
    __shared__ float osm[4][64];
    __shared__ float otot[64];

    // one-time: copy packed Wcat [192][64] -> LDS with pad stride 72
    {
        const unsigned int* wsrc = (const unsigned int*)(ws + WCAT_OFF);
        for (int i = tid; i < 6144; i += 256)
            *(unsigned int*)(Wc + (i >> 5) * 72 + (i & 31) * 2) = wsrc[i];
    }

    // persistent per-lane params for n = t*16+col
    float cK[4], dK[4], cV[4], dV[4], qs[4], pdv[4], beL[4];
    #pragma unroll
    for (int t = 0; t < 4; t++) {
        int n = t * 16 + col;
        cK[t] = ws[8192 + n]; dK[t] = ws[8256 + n];
        cV[t] = ws[8320 + n]; dV[t] = ws[8384 + n];
        qs[t]  = ws[8448 + blk * 64 + n];
        pdv[t] = ws[73984 + blk * 64 + n];
        beL[t] = be[n];
    }
    const float* sv  = ws + 139520 + b * 256;
    const float* ssv = ws + 140544 + b * 256;
    const float* Qsk = ws + 141568 + (size_t)b * 16384;
    const float* Qsv = ws + 207104 + (size_t)b * 16384;
    const float* Ps  = ws + 272640 + (size_t)b * 16384;

    float o0 = 0.f, o1 = 0.f, o2 = 0.f, o3 = 0.f;
    int rstage = tid >> 2, gstage = tid & 3;

    __syncthreads();   // Wc ready (only barrier before epilogue)

    for (int chunk = 0; chunk < 4; chunk++) {
        int s0 = chunk * 64;
        // ---- stage 64 rows of E (fp32 -> bf16) + exact fp32 row stats (wave-local) ----
        {
            const float* ep = E + ((size_t)(((b * 256 + s0 + rstage) * 256 + d))) * 64 + gstage * 16;
            float4 e0 = *(const float4*)(ep);
            float4 e1 = *(const float4*)(ep + 4);
            float4 e2 = *(const float4*)(ep + 8);
            float4 e3 = *(const float4*)(ep + 12);
            float s1 = (e0.x + e0.y + e0.z + e0.w) + (e1.x + e1.y + e1.z + e1.w)
                     + (e2.x + e2.y + e2.z + e2.w) + (e3.x + e3.y + e3.z + e3.w);
            float s2 = (e0.x*e0.x + e0.y*e0.y + e0.z*e0.z + e0.w*e0.w)
                     + (e1.x*e1.x + e1.y*e1.y + e1.z*e1.z + e1.w*e1.w)
                     + (e2.x*e2.x + e2.y*e2.y + e2.z*e2.z + e2.w*e2.w)
                     + (e3.x*e3.x + e3.y*e3.y + e3.z*e3.z + e3.w*e3.w);
            s1 += __shfl_xor(s1, 1); s2 += __shfl_xor(s2, 1);
            s1 += __shfl_xor(s1, 2); s2 += __shfl_xor(s2, 2);
            if (gstage == 0) { ssum[rstage] = s1; sssq[rstage] = s2; }
            ushort8 w0, w1;
            w0[0]=f2bf(e0.x); w0[1]=f2bf(e0.y); w0[2]=f2bf(e0.z); w0[3]=f2bf(e0.w);
            w0[4]=f2bf(e1.x); w0[5]=f2bf(e1.y); w0[6]=f2bf(e1.z); w0[7]=f2bf(e1.w);
            w1[0]=f2bf(e2.x); w1[1]=f2bf(e2.y); w1[2]=f2bf(e2.z); w1[3]=f2bf(e2.w);
            w1[4]=f2bf(e3.x); w1[5]=f2bf(e3.y); w1[6]=f2bf(e3.z); w1[7]=f2bf(e3.w);
            *(ushort8*)(Ebf + rstage * 72 + gstage * 16)     = w0;
            *(ushort8*)(Ebf + rstage * 72 + gstage * 16 + 8) = w1;
        }
        // ---- A fragments (wave-local rows) ----
        short8 a0 = *(const short8*)(Ebf + (wv * 16 + col) * 72 + quad * 8);
        short8 a1 = *(const short8*)(Ebf + (wv * 16 + col) * 72 + 32 + quad * 8);

        // ---- phase 1: qek / qev tiles, accumulators stay in VGPRs ----
        floatx4 ak[4], av[4];
        #pragma unroll
        for (int t = 0; t < 4; t++) {
            const unsigned short* wp = Wc + (t * 16 + col) * 72 + quad * 8;
            floatx4 acc = {0.f, 0.f, 0.f, 0.f};
            acc = __builtin_amdgcn_mfma_f32_16x16x32_bf16(a0, *(const short8*)(wp),      acc, 0, 0, 0);
            acc = __builtin_amdgcn_mfma_f32_16x16x32_bf16(a1, *(const short8*)(wp + 32), acc, 0, 0, 0);
            ak[t] = acc;
        }
        #pragma unroll
        for (int t = 0; t < 4; t++) {
            const unsigned short* wp = Wc + (64 + t * 16 + col) * 72 + quad * 8;
            floatx4 acc = {0.f, 0.f, 0.f, 0.f};
            acc = __builtin_amdgcn_mfma_f32_16x16x32_bf16(a0, *(const short8*)(wp),      acc, 0, 0, 0);
            acc = __builtin_amdgcn_mfma_f32_16x16x32_bf16(a1, *(const short8*)(wp + 32), acc, 0, 0, 0);
            av[t] = acc;
        }

        // ---- phase 2: softmax-over-heads + attention, in MFMA layout ----
        float a_arr[4];
        #pragma unroll
        for (int r = 0; r < 4; r++) {
            int sl = wv * 16 + quad * 4 + r;      // row varies by quad
            int s = s0 + sl;
            float a = A[(b * 256 + s) * 256 + d];
            a_arr[r] = a;
            float mu  = (a * sv[s] + ssum[sl]) * (1.f / 192.f);
            float ex2 = (a * a * ssv[s] + sssq[sl]) * (1.f / 192.f);
            float rsig = rsqrtf(ex2 - mu * mu + EPS);
            float rm = rsig * mu;
            const float* qk = Qsk + s * 64 + col;
            const float* qv = Qsv + s * 64 + col;
            float h0 = qs[0] * fmaxf(rsig * (a * qk[0]  + ak[0][r]) - rm * cK[0] + dK[0], 0.f);
            float h1 = qs[1] * fmaxf(rsig * (a * qk[16] + ak[1][r]) - rm * cK[1] + dK[1], 0.f);
            float h2 = qs[2] * fmaxf(rsig * (a * qk[32] + ak[2][r]) - rm * cK[2] + dK[2], 0.f);
            float h3 = qs[3] * fmaxf(rsig * (a * qk[48] + ak[3][r]) - rm * cK[3] + dK[3], 0.f);
            // dot over dk (lane bits 0..2)
            h0 += __shfl_xor(h0, 1); h1 += __shfl_xor(h1, 1); h2 += __shfl_xor(h2, 1); h3 += __shfl_xor(h3, 1);
            h0 += __shfl_xor(h0, 2); h1 += __shfl_xor(h1, 2); h2 += __shfl_xor(h2, 2); h3 += __shfl_xor(h3, 2);
            h0 += __shfl_xor(h0, 4); h1 += __shfl_xor(h1, 4); h2 += __shfl_xor(h2, 4); h3 += __shfl_xor(h3, 4);
            // softmax over 8 heads: 4 in registers + 1 lane-xor-8
            float m = fmaxf(fmaxf(h0, h1), fmaxf(h2, h3));
            m = fmaxf(m, __shfl_xor(m, 8));
            float p0 = __expf(h0 - m), p1 = __expf(h1 - m), p2 = __expf(h2 - m), p3 = __expf(h3 - m);
            float den = (p0 + p1) + (p2 + p3);
            den += __shfl_xor(den, 8);
            float inv = 1.f / den;
            float vl0 = fmaxf(rsig * (a * qv[0]  + av[0][r]) - rm * cV[0] + dV[0], 0.f);
            float vl1 = fmaxf(rsig * (a * qv[16] + av[1][r]) - rm * cV[1] + dV[1], 0.f);
            float vl2 = fmaxf(rsig * (a * qv[32] + av[2][r]) - rm * cV[2] + dV[2], 0.f);
            float vl3 = fmaxf(rsig * (a * qv[48] + av[3][r]) - rm * cV[3] + dV[3], 0.f);
            o0 += p0 * inv * vl0; o1 += p1 * inv * vl1;
            o2 += p2 * inv * vl2; o3 += p3 * inv * vl3;
        }

        // ---- phase 3: pe tiles + E_new store ----
        floatx4 ap[4];
        #pragma unroll
        for (int t = 0; t < 4; t++) {
            const unsigned short* wp = Wc + (128 + t * 16 + col) * 72 + quad * 8;
            floatx4 acc = {0.f, 0.f, 0.f, 0.f};
            acc = __builtin_amdgcn_mfma_f32_16x16x32_bf16(a0, *(const short8*)(wp),      acc, 0, 0, 0);
            acc = __builtin_amdgcn_mfma_f32_16x16x32_bf16(a1, *(const short8*)(wp + 32), acc, 0, 0, 0);
            ap[t] = acc;
        }
        #pragma unroll
        for (int r = 0; r < 4; r++) {
            int s = s0 + wv * 16 + quad * 4 + r;
            float a = a_arr[r];
            size_t base = ((size_t)((b * 256 + s) * 256 + d)) * 64;
            const float* ps = Ps + s * 64 + col;
            #pragma unroll
            for (int t = 0; t < 4; t++) {
                float val = fmaxf(a * (ps[t * 16] + pdv[t]) + ap[t][r] + beL[t], 0.f);
                out1[base + t * 16 + col] = val;   // 64B-aligned full sectors
            }
        }
    }

    // ---- o reduction: over quads in-register, then cross-wave via LDS ----
    o0 += __shfl_xor(o0, 16); o0 += __shfl_xor(o0, 32);
    o1 += __shfl_xor(o1, 16); o1 += __shfl_xor(o1, 32);
    o2 += __shfl_xor(o2, 16); o2 += __shfl_xor(o2, 32);
    o3 += __shfl_xor(o3, 16); o3 += __shfl_xor(o3, 32);
    float oval = (quad == 0) ? o0 : (quad == 1) ? o1 : ((quad == 2) ? o2 : o3);
    osm[wv][lane] = oval;     // lane = quad*16+col == n
    __syncthreads();
    if (tid < 64) otot[tid] = osm[0][tid] + osm[1][tid] + osm[2][tid] + osm[3][tid];
    __syncthreads();
    if (tid < 128) {
        float acc = bo[tid];
        for (int n = 0; n < 64; n++) acc += otot[n] * Wo[n * 128 + tid];
        out0[blk * 128 + tid] = V_dst[blk * 128 + tid] + fmaxf(acc, 0.f);
    }
}

extern "C" void kernel_launch(void* const* d_in, const int* in_sizes, int n_in,
                              void* d_out, int out_size, void* d_ws, size_t ws_size,
                              hipStream_t stream) {
    (void)in_sizes; (void)n_in; (void)out_size; (void)ws_size;
    const float* V_src = (const float*)d_in[0];
    const float* V_dst = (const float*)d_in[1];
    const float* E     = (const float*)d_in[2];
    const float* A     = (const float*)d_in[3];
    const float* g_vd  = (const float*)d_in[4];
    const float* b_vd  = (const float*)d_in[5];
    const float* g_in  = (const float*)d_in[6];
    const float* b_in  = (const float*)d_in[7];
    const float* Wq    = (const float*)d_in[8];
    const float* bq    = (const float*)d_in[9];
    const float* Wk    = (const float*)d_in[10];
    const float* bk    = (const float*)d_in[11];
    const float* Wv    = (const float*)d_in[12];
    const float* bv    = (const float*)d_in[13];
    const float* Wo    = (const float*)d_in[14];
    const float* bo    = (const float*)d_in[15];
    const float* We    = (const float*)d_in[16];
    const float* be    = (const float*)d_in[17];
    float* ws   = (float*)d_ws;
    float* out0 = (float*)d_out;
    float* out1 = out0 + 131072;            // E_new [B,S,D,64]
    float* out2 = out1 + 16777216;          // A_new [B,S,D]

    hipLaunchKernelGGL(prep_merged, dim3(2049), dim3(256), 0, stream,
                       V_src, V_dst, g_vd, b_vd, g_in, b_in, Wq, bq, Wk, bk, Wv, bv, We, ws, out2);
    hipLaunchKernelGGL(fused_kernel, dim3(1024), dim3(256), 0, stream,
                       E, A, V_dst, Wo, bo, be, ws, out0, out1);
}

// Round 3
// 299.079 us; speedup vs baseline: 1.0112x; 1.0112x over previous
//
#include <hip/hip_runtime.h>
#include <hip/hip_bf16.h>
#include <math.h>

#define EPS 1e-3f
// B=4, S=256, D=256, v=128, e=64, c=192, NH=8, DK=8, DV=8

// ws layout (floats):
// 8192   : cK[64], 8256: dK[64], 8320: cV[64], 8384: dV[64]
// 8448   : q_s [B*D*64]  (relu(q)/sqrt(8))
// 73984  : Pd  [B*D*64]  (V_dst @ We[128:256])
// 139520 : sv  [B*S]     (sum of V_src row)
// 140544 : ssv [B*S]     (sumsq of V_src row)
// 141568 : Qs_k[B*S*64]  (g_in-folded V_src @ Wk[0:128])
// 207104 : Qs_v[B*S*64]
// 272640 : Ps  [B*S*64]  (V_src @ We[0:128])
// 338176 : Wcat bf16 [192 n][64 k]  = [g_in*WkE | g_in*WvE | We3]  (12288 ushort)
#define WCAT_OFF 338176

typedef __attribute__((ext_vector_type(8))) short short8;
typedef __attribute__((ext_vector_type(8))) unsigned short ushort8;
typedef __attribute__((ext_vector_type(4))) float floatx4;

__device__ __forceinline__ unsigned short f2bf(float f) {
    __hip_bfloat16 h = __float2bfloat16(f);
    return *reinterpret_cast<unsigned short*>(&h);
}

// Merged precompute: blocks 0..1023 = dst-mode (+ coalesced A_new=1 fill),
// 1024..2047 = src-mode, 2048 = weight-prep.
__global__ __launch_bounds__(256) void prep_merged(
        const float* __restrict__ V_src, const float* __restrict__ V_dst,
        const float* __restrict__ g_vd, const float* __restrict__ b_vd,
        const float* __restrict__ g_in, const float* __restrict__ b_in,
        const float* __restrict__ Wq, const float* __restrict__ bq,
        const float* __restrict__ Wk, const float* __restrict__ bk,
        const float* __restrict__ Wv, const float* __restrict__ bv,
        const float* __restrict__ We, float* __restrict__ ws,
        float* __restrict__ out2) {
    int blk = blockIdx.x;
    int tid = threadIdx.x;
    __shared__ float sA[128], sB[128], sC[4];
    if (blk < 1024) {
        // ---- dst-mode: LN(V_dst)->q, Pd; plus A_new = 1.0 fill ----
        float x = 0.f;
        if (tid < 128) { x = V_dst[blk * 128 + tid]; sA[tid] = x; }
        float s1 = x, s2 = x * x;
        #pragma unroll
        for (int o = 1; o <= 32; o <<= 1) { s1 += __shfl_xor(s1, o); s2 += __shfl_xor(s2, o); }
        if (tid < 128 && (tid & 63) == 0) { sC[tid >> 6] = s1; sC[2 + (tid >> 6)] = s2; }
        __syncthreads();
        if (tid < 128) {
            float sum = sC[0] + sC[1], ssq = sC[2] + sC[3];
            float mu = sum * (1.f / 128.f);
            float var = ssq * (1.f / 128.f) - mu * mu;
            float rsig = rsqrtf(var + EPS);
            sB[tid] = (x - mu) * rsig * g_vd[tid] + b_vd[tid];
        }
        __syncthreads();
        if (tid < 128) {
            int n = tid & 63;
            if (tid < 64) {
                float acc = bq[n];
                #pragma unroll 4
                for (int j = 0; j < 128; j++) acc += sB[j] * Wq[j * 64 + n];
                ws[8448 + blk * 64 + n] = fmaxf(acc, 0.f) * 0.35355339059327373f;
            } else {
                float acc = 0.f;
                #pragma unroll 4
                for (int j = 0; j < 128; j++) acc += sA[j] * We[(128 + j) * 64 + n];
                ws[73984 + blk * 64 + n] = acc;
            }
        }
        out2[blk * 256 + tid] = 1.0f;   // A_new == softmax over singleton == 1
    } else if (blk < 2048) {
        // ---- src-mode: row stats; Qs_k / Qs_v / Ps ----
        int sb = blk - 1024;
        if (tid < 128) sA[tid] = V_src[sb * 128 + tid];
        __syncthreads();
        if (tid < 64) {
            float a = sA[tid], b2 = sA[tid + 64];
            float s1 = a + b2, s2 = a * a + b2 * b2;
            #pragma unroll
            for (int o = 1; o <= 32; o <<= 1) { s1 += __shfl_xor(s1, o); s2 += __shfl_xor(s2, o); }
            if (tid == 0) { ws[139520 + sb] = s1; ws[140544 + sb] = s2; }
        }
        if (tid < 192) {
            int g = tid / 64, n = tid & 63;
            float acc = 0.f;
            if (g == 0) {
                #pragma unroll 4
                for (int j = 0; j < 128; j++) acc += sA[j] * g_in[j] * Wk[j * 64 + n];
                ws[141568 + sb * 64 + n] = acc;
            } else if (g == 1) {
                #pragma unroll 4
                for (int j = 0; j < 128; j++) acc += sA[j] * g_in[j] * Wv[j * 64 + n];
                ws[207104 + sb * 64 + n] = acc;
            } else {
                #pragma unroll 4
                for (int j = 0; j < 128; j++) acc += sA[j] * We[j * 64 + n];
                ws[272640 + sb * 64 + n] = acc;
            }
        }
    } else {
        // ---- weight-prep (folded LN coefficients + bf16 Wcat) ----
        int n = tid & 63;
        if (tid < 64) {
            float c = 0.f, dd = 0.f;
            for (int j = 0; j < 192; j++) { float w = Wk[j * 64 + n]; c += g_in[j] * w; dd += b_in[j] * w; }
            ws[8192 + n] = c; ws[8256 + n] = dd + bk[n];
        } else if (tid < 128) {
            float c = 0.f, dd = 0.f;
            for (int j = 0; j < 192; j++) { float w = Wv[j * 64 + n]; c += g_in[j] * w; dd += b_in[j] * w; }
            ws[8320 + n] = c; ws[8384 + n] = dd + bv[n];
        }
        unsigned short* wcat = (unsigned short*)(ws + WCAT_OFF);
        for (int idx = tid; idx < 12288; idx += 256) {
            int nn = idx >> 6, k = idx & 63;
            float w;
            if (nn < 64)       w = g_in[128 + k] * Wk[(128 + k) * 64 + nn];
            else if (nn < 128) w = g_in[128 + k] * Wv[(128 + k) * 64 + (nn - 64)];
            else               w = We[(256 + k) * 64 + (nn - 128)];
            wcat[idx] = f2bf(w);
        }
    }
}

// Fused per-(b,d) kernel, MFMA-layout epilogue (no res[] transpose).
//   n = t*16+col  ->  dk = col&7 (shfl_xor 1,2,4), head = t*2 + (col>>3)
// Round-2 changes (unmeasured last round — broker timeout; resubmitted verbatim):
//  - bijective XCD swizzle: XCD x owns contiguous work [x*128,(x+1)*128)
//    (half a batch) so Qsk/Qsv/Ps/A stay resident in that XCD's L2.
//  - Qs/A loads hoisted to chunk start into registers: latency overlaps
//    E-staging + phase-1 MFMAs instead of the phase-2 dependent chain.
__global__ __launch_bounds__(256, 4) void fused_kernel(
        const float* __restrict__ E, const float* __restrict__ A,
        const float* __restrict__ V_dst,
        const float* __restrict__ Wo, const float* __restrict__ bo,
        const float* __restrict__ be,
        const float* __restrict__ ws,
        float* __restrict__ out0, float* __restrict__ out1) {
    int blk = ((blockIdx.x & 7) << 7) | (blockIdx.x >> 3);   // XCD-contiguous work id
    int b = blk >> 8, d = blk & 255;
    int tid = threadIdx.x, wv = tid >> 6, lane = tid & 63;
    int col = lane & 15, quad = lane >> 4;

    __shared__ __align__(16) unsigned short Ebf[64 * 72];   // 64 rows x 64 bf16, stride 72
    __shared__ __align__(16) unsigned short Wc[192 * 72];   // Wcat, stride 72
    __shared__ float ssum[64], sssq[64];
    __shared__ float osm[4][64];
    __shared__ float otot[64];

    // one-time: copy packed Wcat [192][64] -> LDS with pad stride 72
    {
        const unsigned int* wsrc = (const unsigned int*)(ws + WCAT_OFF);
        for (int i = tid; i < 6144; i += 256)
            *(unsigned int*)(Wc + (i >> 5) * 72 + (i & 31) * 2) = wsrc[i];
    }

    // persistent per-lane params for n = t*16+col
    float cK[4], dK[4], cV[4], dV[4], qs[4], pdv[4], beL[4];
    #pragma unroll
    for (int t = 0; t < 4; t++) {
        int n = t * 16 + col;
        cK[t] = ws[8192 + n]; dK[t] = ws[8256 + n];
        cV[t] = ws[8320 + n]; dV[t] = ws[8384 + n];
        qs[t]  = ws[8448 + blk * 64 + n];
        pdv[t] = ws[73984 + blk * 64 + n];
        beL[t] = be[n];
    }
    const float* sv  = ws + 139520 + b * 256;
    const float* ssv = ws + 140544 + b * 256;
    const float* Qsk = ws + 141568 + (size_t)b * 16384;
    const float* Qsv = ws + 207104 + (size_t)b * 16384;
    const float* Ps  = ws + 272640 + (size_t)b * 16384;

    float o0 = 0.f, o1 = 0.f, o2 = 0.f, o3 = 0.f;
    int rstage = tid >> 2, gstage = tid & 3;

    __syncthreads();   // Wc ready (only barrier before epilogue)

    for (int chunk = 0; chunk < 4; chunk++) {
        int s0 = chunk * 64;
        // ---- stage 64 rows of E (fp32 -> bf16) + exact fp32 row stats (wave-local) ----
        {
            const float* ep = E + ((size_t)(((b * 256 + s0 + rstage) * 256 + d))) * 64 + gstage * 16;
            float4 e0 = *(const float4*)(ep);
            float4 e1 = *(const float4*)(ep + 4);
            float4 e2 = *(const float4*)(ep + 8);
            float4 e3 = *(const float4*)(ep + 12);
            float s1 = (e0.x + e0.y + e0.z + e0.w) + (e1.x + e1.y + e1.z + e1.w)
                     + (e2.x + e2.y + e2.z + e2.w) + (e3.x + e3.y + e3.z + e3.w);
            float s2 = (e0.x*e0.x + e0.y*e0.y + e0.z*e0.z + e0.w*e0.w)
                     + (e1.x*e1.x + e1.y*e1.y + e1.z*e1.z + e1.w*e1.w)
                     + (e2.x*e2.x + e2.y*e2.y + e2.z*e2.z + e2.w*e2.w)
                     + (e3.x*e3.x + e3.y*e3.y + e3.z*e3.z + e3.w*e3.w);
            s1 += __shfl_xor(s1, 1); s2 += __shfl_xor(s2, 1);
            s1 += __shfl_xor(s1, 2); s2 += __shfl_xor(s2, 2);
            if (gstage == 0) { ssum[rstage] = s1; sssq[rstage] = s2; }
            ushort8 w0, w1;
            w0[0]=f2bf(e0.x); w0[1]=f2bf(e0.y); w0[2]=f2bf(e0.z); w0[3]=f2bf(e0.w);
            w0[4]=f2bf(e1.x); w0[5]=f2bf(e1.y); w0[6]=f2bf(e1.z); w0[7]=f2bf(e1.w);
            w1[0]=f2bf(e2.x); w1[1]=f2bf(e2.y); w1[2]=f2bf(e2.z); w1[3]=f2bf(e2.w);
            w1[4]=f2bf(e3.x); w1[5]=f2bf(e3.y); w1[6]=f2bf(e3.z); w1[7]=f2bf(e3.w);
            *(ushort8*)(Ebf + rstage * 72 + gstage * 16)     = w0;
            *(ushort8*)(Ebf + rstage * 72 + gstage * 16 + 8) = w1;
        }

        // ---- hoisted epilogue loads: issued early, consumed in phase 2 ----
        float qkL[4][4], qvL[4][4], aL[4];
        #pragma unroll
        for (int r = 0; r < 4; r++) {
            int s = s0 + wv * 16 + quad * 4 + r;
            aL[r] = A[(b * 256 + s) * 256 + d];
            const float* qk = Qsk + s * 64 + col;
            const float* qv = Qsv + s * 64 + col;
            #pragma unroll
            for (int t = 0; t < 4; t++) { qkL[r][t] = qk[t * 16]; qvL[r][t] = qv[t * 16]; }
        }

        // ---- A fragments (wave-local rows) ----
        short8 a0 = *(const short8*)(Ebf + (wv * 16 + col) * 72 + quad * 8);
        short8 a1 = *(const short8*)(Ebf + (wv * 16 + col) * 72 + 32 + quad * 8);

        // ---- phase 1: qek / qev tiles, accumulators stay in VGPRs ----
        floatx4 ak[4], av[4];
        #pragma unroll
        for (int t = 0; t < 4; t++) {
            const unsigned short* wp = Wc + (t * 16 + col) * 72 + quad * 8;
            floatx4 acc = {0.f, 0.f, 0.f, 0.f};
            acc = __builtin_amdgcn_mfma_f32_16x16x32_bf16(a0, *(const short8*)(wp),      acc, 0, 0, 0);
            acc = __builtin_amdgcn_mfma_f32_16x16x32_bf16(a1, *(const short8*)(wp + 32), acc, 0, 0, 0);
            ak[t] = acc;
        }
        #pragma unroll
        for (int t = 0; t < 4; t++) {
            const unsigned short* wp = Wc + (64 + t * 16 + col) * 72 + quad * 8;
            floatx4 acc = {0.f, 0.f, 0.f, 0.f};
            acc = __builtin_amdgcn_mfma_f32_16x16x32_bf16(a0, *(const short8*)(wp),      acc, 0, 0, 0);
            acc = __builtin_amdgcn_mfma_f32_16x16x32_bf16(a1, *(const short8*)(wp + 32), acc, 0, 0, 0);
            av[t] = acc;
        }

        // ---- phase 2: softmax-over-heads + attention, in MFMA layout ----
        #pragma unroll
        for (int r = 0; r < 4; r++) {
            int sl = wv * 16 + quad * 4 + r;
            int s = s0 + sl;
            float a = aL[r];
            float mu  = (a * sv[s] + ssum[sl]) * (1.f / 192.f);
            float ex2 = (a * a * ssv[s] + sssq[sl]) * (1.f / 192.f);
            float rsig = rsqrtf(ex2 - mu * mu + EPS);
            float rm = rsig * mu;
            float h0 = qs[0] * fmaxf(rsig * (a * qkL[r][0] + ak[0][r]) - rm * cK[0] + dK[0], 0.f);
            float h1 = qs[1] * fmaxf(rsig * (a * qkL[r][1] + ak[1][r]) - rm * cK[1] + dK[1], 0.f);
            float h2 = qs[2] * fmaxf(rsig * (a * qkL[r][2] + ak[2][r]) - rm * cK[2] + dK[2], 0.f);
            float h3 = qs[3] * fmaxf(rsig * (a * qkL[r][3] + ak[3][r]) - rm * cK[3] + dK[3], 0.f);
            // dot over dk (lane bits 0..2)
            h0 += __shfl_xor(h0, 1); h1 += __shfl_xor(h1, 1); h2 += __shfl_xor(h2, 1); h3 += __shfl_xor(h3, 1);
            h0 += __shfl_xor(h0, 2); h1 += __shfl_xor(h1, 2); h2 += __shfl_xor(h2, 2); h3 += __shfl_xor(h3, 2);
            h0 += __shfl_xor(h0, 4); h1 += __shfl_xor(h1, 4); h2 += __shfl_xor(h2, 4); h3 += __shfl_xor(h3, 4);
            // softmax over 8 heads: 4 in registers + 1 lane-xor-8
            float m = fmaxf(fmaxf(h0, h1), fmaxf(h2, h3));
            m = fmaxf(m, __shfl_xor(m, 8));
            float p0 = __expf(h0 - m), p1 = __expf(h1 - m), p2 = __expf(h2 - m), p3 = __expf(h3 - m);
            float den = (p0 + p1) + (p2 + p3);
            den += __shfl_xor(den, 8);
            float inv = 1.f / den;
            float vl0 = fmaxf(rsig * (a * qvL[r][0] + av[0][r]) - rm * cV[0] + dV[0], 0.f);
            float vl1 = fmaxf(rsig * (a * qvL[r][1] + av[1][r]) - rm * cV[1] + dV[1], 0.f);
            float vl2 = fmaxf(rsig * (a * qvL[r][2] + av[2][r]) - rm * cV[2] + dV[2], 0.f);
            float vl3 = fmaxf(rsig * (a * qvL[r][3] + av[3][r]) - rm * cV[3] + dV[3], 0.f);
            o0 += p0 * inv * vl0; o1 += p1 * inv * vl1;
            o2 += p2 * inv * vl2; o3 += p3 * inv * vl3;
        }

        // ---- phase 3: pe tiles + E_new store ----
        floatx4 ap[4];
        #pragma unroll
        for (int t = 0; t < 4; t++) {
            const unsigned short* wp = Wc + (128 + t * 16 + col) * 72 + quad * 8;
            floatx4 acc = {0.f, 0.f, 0.f, 0.f};
            acc = __builtin_amdgcn_mfma_f32_16x16x32_bf16(a0, *(const short8*)(wp),      acc, 0, 0, 0);
            acc = __builtin_amdgcn_mfma_f32_16x16x32_bf16(a1, *(const short8*)(wp + 32), acc, 0, 0, 0);
            ap[t] = acc;
        }
        #pragma unroll
        for (int r = 0; r < 4; r++) {
            int s = s0 + wv * 16 + quad * 4 + r;
            float a = aL[r];
            size_t base = ((size_t)((b * 256 + s) * 256 + d)) * 64;
            const float* ps = Ps + s * 64 + col;
            #pragma unroll
            for (int t = 0; t < 4; t++) {
                float val = fmaxf(a * (ps[t * 16] + pdv[t]) + ap[t][r] + beL[t], 0.f);
                out1[base + t * 16 + col] = val;
            }
        }
    }

    // ---- o reduction: over quads in-register, then cross-wave via LDS ----
    o0 += __shfl_xor(o0, 16); o0 += __shfl_xor(o0, 32);
    o1 += __shfl_xor(o1, 16); o1 += __shfl_xor(o1, 32);
    o2 += __shfl_xor(o2, 16); o2 += __shfl_xor(o2, 32);
    o3 += __shfl_xor(o3, 16); o3 += __shfl_xor(o3, 32);
    float oval = (quad == 0) ? o0 : (quad == 1) ? o1 : ((quad == 2) ? o2 : o3);
    osm[wv][lane] = oval;     // lane = quad*16+col == n
    __syncthreads();
    if (tid < 64) otot[tid] = osm[0][tid] + osm[1][tid] + osm[2][tid] + osm[3][tid];
    __syncthreads();
    if (tid < 128) {
        float acc = bo[tid];
        #pragma unroll 4
        for (int n = 0; n < 64; n++) acc += otot[n] * Wo[n * 128 + tid];
        out0[blk * 128 + tid] = V_dst[blk * 128 + tid] + fmaxf(acc, 0.f);
    }
}

extern "C" void kernel_launch(void* const* d_in, const int* in_sizes, int n_in,
                              void* d_out, int out_size, void* d_ws, size_t ws_size,
                              hipStream_t stream) {
    (void)in_sizes; (void)n_in; (void)out_size; (void)ws_size;
    const float* V_src = (const float*)d_in[0];
    const float* V_dst = (const float*)d_in[1];
    const float* E     = (const float*)d_in[2];
    const float* A     = (const float*)d_in[3];
    const float* g_vd  = (const float*)d_in[4];
    const float* b_vd  = (const float*)d_in[5];
    const float* g_in  = (const float*)d_in[6];
    const float* b_in  = (const float*)d_in[7];
    const float* Wq    = (const float*)d_in[8];
    const float* bq    = (const float*)d_in[9];
    const float* Wk    = (const float*)d_in[10];
    const float* bk    = (const float*)d_in[11];
    const float* Wv    = (const float*)d_in[12];
    const float* bv    = (const float*)d_in[13];
    const float* Wo    = (const float*)d_in[14];
    const float* bo    = (const float*)d_in[15];
    const float* We    = (const float*)d_in[16];
    const float* be    = (const float*)d_in[17];
    float* ws   = (float*)d_ws;
    float* out0 = (float*)d_out;
    float* out1 = out0 + 131072;            // E_new [B,S,D,64]
    float* out2 = out1 + 16777216;          // A_new [B,S,D]

    hipLaunchKernelGGL(prep_merged, dim3(2049), dim3(256), 0, stream,
                       V_src, V_dst, g_vd, b_vd, g_in, b_in, Wq, bq, Wk, bk, Wv, bv, We, ws, out2);
    hipLaunchKernelGGL(fused_kernel, dim3(1024), dim3(256), 0, stream,
                       E, A, V_dst, Wo, bo, be, ws, out0, out1);
}